// Round 5
// baseline (724.456 us; speedup 1.0000x reference)
//
#include <hip/hip_runtime.h>

typedef __attribute__((ext_vector_type(8))) short short8;
typedef __attribute__((ext_vector_type(4))) float f32x4;
typedef unsigned short ushort_t;
typedef unsigned int uint32;

// ---------- constants ----------
#define N0 30000
#define N1 90000
#define N2 60000
#define P0 30208   // 236*128
#define S1OFF 30208
#define S2OFF 120320
#define MPAD 180352  // P0+P1+P2
#define MT_ALL 1409  // MPAD/128
#define NE0 960000
#define NE1 180000
#define NE2 180000
#define CSTRIDE 30720  // per-level cur/rowPtr stride (>= N0+1)

__device__ __forceinline__ float bf2f(ushort_t u) {
    union { uint32 i; float f; } v; v.i = ((uint32)u) << 16; return v.f;
}
__device__ __forceinline__ ushort_t f2bf(float f) {
    union { float f; uint32 i; } v; v.f = f;
    uint32 x = v.i;
    x += ((x >> 16) & 1u) + 0x7FFFu;   // RNE
    return (ushort_t)(x >> 16);
}

// ---------- prep: weights -> bf16 transposed layouts ----------
__global__ __launch_bounds__(256) void prep_w(const float* __restrict__ W1,
                                              const float* __restrict__ Wagg,
                                              const float* __restrict__ bagg,
                                              ushort_t* __restrict__ W1t,   // [4][128][256]
                                              ushort_t* __restrict__ Wgt,   // [4][3][128][128]
                                              ushort_t* __restrict__ WgtC,  // [128][512]
                                              float* __restrict__ bsum) {   // [128]
    int idx = blockIdx.x * blockDim.x + threadIdx.x;
    if (idx < 131072) {  // W1t[h][n][k] = W1[h][k][n]
        int h = idx >> 15, rem = idx & 32767, n = rem >> 8, k = rem & 255;
        W1t[idx] = f2bf(W1[((size_t)h * 256 + k) * 128 + n]);
    }
    if (idx < 196608) {  // Wgt[h][l][n][k] = Wagg[h][(l+1)*128+k][n]
        int h = idx / 49152, rem = idx % 49152;
        int l = rem / 16384, rem2 = rem % 16384, n = rem2 >> 7, k = rem2 & 127;
        Wgt[idx] = f2bf(Wagg[((size_t)h * 512 + (l + 1) * 128 + k) * 128 + n]);
    }
    if (idx < 65536) {   // WgtC[n][h*128+k] = Wagg[h][k][n]  (block 0)
        int n = idx >> 9, kk = idx & 511, h = kk >> 7, k = kk & 127;
        WgtC[idx] = f2bf(Wagg[((size_t)h * 512 + k) * 128 + n]);
    }
    if (idx < 128) {
        float s = 0.f;
        #pragma unroll
        for (int h = 0; h < 4; ++h) s += bagg[h * 128 + idx];
        bsum[idx] = s;
    }
}

// ---------- CSR build (per level) ----------
__global__ __launch_bounds__(256) void csr_zero(int* __restrict__ cur) {
    int i = blockIdx.x * blockDim.x + threadIdx.x;
    if (i < 3 * CSTRIDE) cur[i] = 0;
}

__global__ __launch_bounds__(256) void csr_hist(const int* __restrict__ rows, int nE,
                                                int* __restrict__ cur) {
    int i = blockIdx.x * blockDim.x + threadIdx.x;
    if (i < nE) atomicAdd(cur + rows[i], 1);
}

// 3 blocks, one per level: exclusive scan of cur -> rowPtr & cur
__global__ __launch_bounds__(1024) void csr_scan(int* __restrict__ curA,
                                                 int* __restrict__ rowPtrA,
                                                 int nE0, int nE1, int nE2) {
    __shared__ int ssum[1024];
    const int b = blockIdx.x;
    int* cur = curA + b * CSTRIDE;
    int* rowPtr = rowPtrA + b * CSTRIDE;
    const int nE = (b == 0) ? nE0 : (b == 1 ? nE1 : nE2);
    const int t = threadIdx.x;
    const int base = t * 30;          // 1024*30 = 30720 >= N0
    int loc[30];
    int s = 0;
    #pragma unroll
    for (int i = 0; i < 30; ++i) {
        int r = base + i;
        int v = (r < N0) ? cur[r] : 0;
        loc[i] = s; s += v;
    }
    ssum[t] = s;
    __syncthreads();
    for (int off = 1; off < 1024; off <<= 1) {
        int v = (t >= off) ? ssum[t - off] : 0;
        __syncthreads();
        ssum[t] += v;
        __syncthreads();
    }
    int carry = (t == 0) ? 0 : ssum[t - 1];
    #pragma unroll
    for (int i = 0; i < 30; ++i) {
        int r = base + i;
        if (r < N0) {
            int p = carry + loc[i];
            rowPtr[r] = p;
            cur[r] = p;
        }
    }
    if (t == 0) rowPtr[N0] = nE;
}

__global__ __launch_bounds__(256) void csr_scatter(const int* __restrict__ rows,
                                                   const int* __restrict__ cols,
                                                   int nE, int Sl,
                                                   int* __restrict__ cur,
                                                   int* __restrict__ sortedCg) {
    int i = blockIdx.x * blockDim.x + threadIdx.x;
    if (i < nE) {
        int pos = atomicAdd(cur + rows[i], 1);
        sortedCg[pos] = Sl + cols[i];
    }
}

// ---------- fused: Y=relu(XW1+b) (regs) -> attn dots + z-proj + out-init ----------
// 512 threads = 8 waves (2x4); 128-row tile; As/Ys XOR-swizzled; B-frags from L2.
__global__ __launch_bounds__(512, 1)
void gemm_fused(const float* __restrict__ x0,
                const float* __restrict__ x1,
                const float* __restrict__ x2,
                const ushort_t* __restrict__ W1t,
                const float* __restrict__ b1,
                const ushort_t* __restrict__ Wgt,
                const ushort_t* __restrict__ WgtC,
                const float* __restrict__ bsum,
                const float* __restrict__ a1w, const float* __restrict__ a1b,
                const float* __restrict__ a2w, const float* __restrict__ a2b,
                float* __restrict__ a1o, float* __restrict__ a2o,
                ushort_t* __restrict__ Z, float* __restrict__ outF)
{
    __shared__ ushort_t As[128 * 256];   // X tile bf16, swizzled: chunk c -> c^(row&7)
    __shared__ ushort_t Ys[128 * 128];   // per-head Y tile, swizzled
    const int tid = threadIdx.x;
    const int lane = tid & 63;
    const int wid = tid >> 6;
    const int wm = wid >> 2, wn = wid & 3;   // wave tile 64x32
    const int l15 = lane & 15, lg = lane >> 4;
    const int r0 = blockIdx.x * 128;
    const bool isL0 = (r0 < P0);
    const int l = isL0 ? 0 : (r0 < S2OFF ? 1 : 2);

    const float* src; int jbase, nreal;
    if (l == 0)      { src = x0; jbase = r0;         nreal = N0; }
    else if (l == 1) { src = x1; jbase = r0 - S1OFF; nreal = N1; }
    else             { src = x2; jbase = r0 - S2OFF; nreal = N2; }

    // stage As once: f32 -> bf16, swizzled (4096 16B-chunks, 8 per thread)
    #pragma unroll
    for (int p = 0; p < 8; ++p) {
        int chunk = tid + p * 512;
        int row = chunk >> 5, c = chunk & 31;
        int j = jbase + row;
        ushort_t o[8] __attribute__((aligned(16)));
        if (j < nreal) {
            const float4 v0 = *(const float4*)(src + (size_t)j * 256 + c * 8);
            const float4 v1 = *(const float4*)(src + (size_t)j * 256 + c * 8 + 4);
            o[0] = f2bf(v0.x); o[1] = f2bf(v0.y); o[2] = f2bf(v0.z); o[3] = f2bf(v0.w);
            o[4] = f2bf(v1.x); o[5] = f2bf(v1.y); o[6] = f2bf(v1.z); o[7] = f2bf(v1.w);
        } else {
            #pragma unroll
            for (int i = 0; i < 8; ++i) o[i] = 0;
        }
        int cs = c ^ (row & 7);
        *(uint4*)(As + row * 256 + cs * 8) = *(const uint4*)o;
    }
    __syncthreads();

    f32x4 oacc[4][2] = {};   // level-0 out-init accumulator (across heads)

    for (int h = 0; h < 4; ++h) {
        // ---- Y = X @ W1_h  (K=256, B-frags from L2, NO barriers) ----
        f32x4 acc[4][2] = {};
        const ushort_t* Bw = W1t + h * 32768;
        #pragma unroll 2
        for (int kt = 0; kt < 8; ++kt) {
            short8 bf[2];
            #pragma unroll
            for (int n = 0; n < 2; ++n) {
                int row = wn * 32 + n * 16 + l15;
                bf[n] = *(const short8*)(Bw + row * 256 + kt * 32 + lg * 8);
            }
            short8 af[4];
            #pragma unroll
            for (int m = 0; m < 4; ++m) {
                int row = wm * 64 + m * 16 + l15;
                int c = (kt * 4 + lg) ^ (row & 7);
                af[m] = *(const short8*)(As + row * 256 + c * 8);
            }
            #pragma unroll
            for (int m = 0; m < 4; ++m)
                #pragma unroll
                for (int n = 0; n < 2; ++n)
                    acc[m][n] = __builtin_amdgcn_mfma_f32_16x16x32_bf16(af[m], bf[n], acc[m][n], 0, 0, 0);
        }
        // epilogue: bias + relu -> Ys (bf16, swizzled)
        #pragma unroll
        for (int n = 0; n < 2; ++n) {
            int col = wn * 32 + n * 16 + l15;
            float bb = b1[h * 128 + col];
            #pragma unroll
            for (int m = 0; m < 4; ++m)
            #pragma unroll
            for (int j = 0; j < 4; ++j) {
                int row = wm * 64 + m * 16 + lg * 4 + j;
                float v = acc[m][n][j] + bb;
                v = v > 0.f ? v : 0.f;
                int cs = (col >> 3) ^ (row & 7);
                Ys[row * 128 + cs * 8 + (col & 7)] = f2bf(v);
            }
        }
        __syncthreads();

        // ---- attention-coefficient dots (4 threads per row) ----
        {
            int row = tid >> 2, q = tid & 3;
            float d1 = 0.f, d2 = 0.f;
            #pragma unroll
            for (int i = 0; i < 4; ++i) {
                int c = (q * 4 + i) ^ (row & 7);
                short8 v = *(const short8*)(Ys + row * 128 + c * 8);
                #pragma unroll
                for (int jj = 0; jj < 8; ++jj) {
                    float f = bf2f(((const ushort_t*)&v)[jj]);
                    int kk = h * 128 + q * 32 + i * 8 + jj;
                    d2 += f * a2w[kk];
                    d1 += f * a1w[kk];
                }
            }
            d1 += __shfl_xor(d1, 1); d1 += __shfl_xor(d1, 2);
            d2 += __shfl_xor(d2, 1); d2 += __shfl_xor(d2, 2);
            if (q == 0) {
                a2o[(size_t)h * MPAD + r0 + row] = d2 + a2b[h];
                if (isL0) a1o[(size_t)h * P0 + r0 + row] = d1 + a1b[h];
            }
        }

        // ---- z = Ys @ Wg_{l,h}  (K=128) ----
        {
            f32x4 zacc[4][2] = {};
            const ushort_t* Bz = Wgt + ((h * 3 + l) << 14);
            #pragma unroll 2
            for (int kt = 0; kt < 4; ++kt) {
                short8 bf[2];
                #pragma unroll
                for (int n = 0; n < 2; ++n) {
                    int row = wn * 32 + n * 16 + l15;
                    bf[n] = *(const short8*)(Bz + row * 128 + kt * 32 + lg * 8);
                }
                short8 af[4];
                #pragma unroll
                for (int m = 0; m < 4; ++m) {
                    int row = wm * 64 + m * 16 + l15;
                    int c = (kt * 4 + lg) ^ (row & 7);
                    af[m] = *(const short8*)(Ys + row * 128 + c * 8);
                }
                #pragma unroll
                for (int m = 0; m < 4; ++m)
                    #pragma unroll
                    for (int n = 0; n < 2; ++n)
                        zacc[m][n] = __builtin_amdgcn_mfma_f32_16x16x32_bf16(af[m], bf[n], zacc[m][n], 0, 0, 0);
            }
            #pragma unroll
            for (int n = 0; n < 2; ++n)
            #pragma unroll
            for (int m = 0; m < 4; ++m)
            #pragma unroll
            for (int j = 0; j < 4; ++j) {
                int row = wm * 64 + m * 16 + lg * 4 + j;
                int col = wn * 32 + n * 16 + l15;
                Z[(size_t)(r0 + row) * 512 + h * 128 + col] = f2bf(zacc[m][n][j]);
            }
        }

        // ---- out-init accumulation (level-0 blocks): oacc += Ys @ WgC_h ----
        if (isL0) {
            #pragma unroll 2
            for (int kt = 0; kt < 4; ++kt) {
                short8 bf[2];
                #pragma unroll
                for (int n = 0; n < 2; ++n) {
                    int row = wn * 32 + n * 16 + l15;
                    bf[n] = *(const short8*)(WgtC + row * 512 + h * 128 + kt * 32 + lg * 8);
                }
                short8 af[4];
                #pragma unroll
                for (int m = 0; m < 4; ++m) {
                    int row = wm * 64 + m * 16 + l15;
                    int c = (kt * 4 + lg) ^ (row & 7);
                    af[m] = *(const short8*)(Ys + row * 128 + c * 8);
                }
                #pragma unroll
                for (int m = 0; m < 4; ++m)
                    #pragma unroll
                    for (int n = 0; n < 2; ++n)
                        oacc[m][n] = __builtin_amdgcn_mfma_f32_16x16x32_bf16(af[m], bf[n], oacc[m][n], 0, 0, 0);
            }
        }
        __syncthreads();   // Ys dead; next head may overwrite
    }

    // ---- out init write (level-0 blocks) ----
    if (isL0) {
        #pragma unroll
        for (int n = 0; n < 2; ++n) {
            int col = wn * 32 + n * 16 + l15;
            float bs = bsum[col];
            #pragma unroll
            for (int m = 0; m < 4; ++m)
            #pragma unroll
            for (int j = 0; j < 4; ++j) {
                int row = r0 + wm * 64 + m * 16 + lg * 4 + j;
                if (row < N0) outF[(size_t)row * 128 + col] = 0.25f * (oacc[m][n][j] + bs);
            }
        }
    }
}

// ---------- pull aggregation: one wave per output row, no atomics ----------
__global__ __launch_bounds__(256) void pull_agg(const int* __restrict__ rowPtr,
                                                const int* __restrict__ sortedCg,
                                                const float* __restrict__ a1,
                                                const float* __restrict__ a2,
                                                const ushort_t* __restrict__ z,
                                                float* __restrict__ out) {
    int w = blockIdx.x * 4 + (threadIdx.x >> 6);
    if (w >= N0) return;
    const int lane = threadIdx.x & 63;
    const int h = lane >> 4, g = lane & 15;

    const float a1r = a1[(size_t)h * P0 + w];
    const float* a2h = a2 + (size_t)h * MPAD;
    int beg = rowPtr[w], end = rowPtr[w + 1];

    float acc[8] = {0.f, 0.f, 0.f, 0.f, 0.f, 0.f, 0.f, 0.f};
    int e = beg;
    for (; e + 1 < end; e += 2) {
        int cg0 = sortedCg[e], cg1 = sortedCg[e + 1];
        float s0 = a1r + a2h[cg0];
        float s1 = a1r + a2h[cg1];
        float att0 = 0.25f / (1.f + __expf(-s0));
        float att1 = 0.25f / (1.f + __expf(-s1));
        uint4 v0 = *(const uint4*)(z + (size_t)cg0 * 512 + lane * 8);
        uint4 v1 = *(const uint4*)(z + (size_t)cg1 * 512 + lane * 8);
        const ushort_t* u0 = (const ushort_t*)&v0;
        const ushort_t* u1 = (const ushort_t*)&v1;
        #pragma unroll
        for (int j = 0; j < 8; ++j)
            acc[j] += att0 * bf2f(u0[j]) + att1 * bf2f(u1[j]);
    }
    if (e < end) {
        int cg = sortedCg[e];
        float s = a1r + a2h[cg];
        float att = 0.25f / (1.f + __expf(-s));
        uint4 v = *(const uint4*)(z + (size_t)cg * 512 + lane * 8);
        const ushort_t* u = (const ushort_t*)&v;
        #pragma unroll
        for (int j = 0; j < 8; ++j) acc[j] += att * bf2f(u[j]);
    }
    #pragma unroll
    for (int j = 0; j < 8; ++j) {
        acc[j] += __shfl_xor(acc[j], 16);
        acc[j] += __shfl_xor(acc[j], 32);
    }
    float2* p = (float2*)(out + (size_t)w * 128 + g * 8 + h * 2);
    float2 o = *p;
    o.x += acc[h * 2 + 0];
    o.y += acc[h * 2 + 1];
    *p = o;
}

extern "C" void kernel_launch(void* const* d_in, const int* in_sizes, int n_in,
                              void* d_out, int out_size, void* d_ws, size_t ws_size,
                              hipStream_t stream) {
    const float* x0   = (const float*)d_in[0];
    const float* x1   = (const float*)d_in[1];
    const float* x2   = (const float*)d_in[2];
    const int* rows0  = (const int*)d_in[3];
    const int* cols0  = (const int*)d_in[4];
    const int* rows1  = (const int*)d_in[5];
    const int* cols1  = (const int*)d_in[6];
    const int* rows2  = (const int*)d_in[7];
    const int* cols2  = (const int*)d_in[8];
    const float* W1   = (const float*)d_in[9];
    const float* b1   = (const float*)d_in[10];
    const float* a1w  = (const float*)d_in[11];
    const float* a1b  = (const float*)d_in[12];
    const float* a2w  = (const float*)d_in[13];
    const float* a2b  = (const float*)d_in[14];
    const float* Wagg = (const float*)d_in[15];
    const float* bagg = (const float*)d_in[16];
    float* out = (float*)d_out;
    char* ws = (char*)d_ws;

    // workspace layout — total 194,853,632 B
    ushort_t* Z      = (ushort_t*)(ws);               // [MPAD][512] bf16 = 184,680,448
    float*    a1o    = (float*)(ws + 184680448);      // [4][P0]   483,328
    float*    a2o    = (float*)(ws + 185163776);      // [4][MPAD] 2,885,632
    ushort_t* W1t    = (ushort_t*)(ws + 188049408);   // 262,144
    ushort_t* Wgt    = (ushort_t*)(ws + 188311552);   // 393,216
    ushort_t* WgtC   = (ushort_t*)(ws + 188704768);   // 131,072
    float*    bsum   = (float*)(ws + 188835840);      // 512
    int*      cur    = (int*)(ws + 188836352);        // [3][CSTRIDE] 368,640
    int*      rowPtr = (int*)(ws + 189204992);        // [3][CSTRIDE] 368,640
    int*      srtCg  = (int*)(ws + 189573632);        // [NNZ_ALL] 5,280,000

    int* cur0 = cur,    * cur1 = cur + CSTRIDE,    * cur2 = cur + 2 * CSTRIDE;
    int* rp0  = rowPtr, * rp1  = rowPtr + CSTRIDE, * rp2  = rowPtr + 2 * CSTRIDE;
    int* srt0 = srtCg,  * srt1 = srtCg + NE0,      * srt2 = srtCg + NE0 + NE1;

    // 1) per-level CSR build (independent of GEMM chain)
    csr_zero<<<(3 * CSTRIDE + 255) / 256, 256, 0, stream>>>(cur);
    csr_hist<<<(NE0 + 255) / 256, 256, 0, stream>>>(rows0, NE0, cur0);
    csr_hist<<<(NE1 + 255) / 256, 256, 0, stream>>>(rows1, NE1, cur1);
    csr_hist<<<(NE2 + 255) / 256, 256, 0, stream>>>(rows2, NE2, cur2);
    csr_scan<<<3, 1024, 0, stream>>>(cur, rowPtr, NE0, NE1, NE2);
    csr_scatter<<<(NE0 + 255) / 256, 256, 0, stream>>>(rows0, cols0, NE0, 0,     cur0, srt0);
    csr_scatter<<<(NE1 + 255) / 256, 256, 0, stream>>>(rows1, cols1, NE1, S1OFF, cur1, srt1);
    csr_scatter<<<(NE2 + 255) / 256, 256, 0, stream>>>(rows2, cols2, NE2, S2OFF, cur2, srt2);

    // 2) weight prep + fused GEMM chain (writes Z, a1o, a2o, out-init)
    prep_w<<<768, 256, 0, stream>>>(W1, Wagg, bagg, W1t, Wgt, WgtC, bsum);
    gemm_fused<<<MT_ALL, 512, 0, stream>>>(x0, x1, x2, W1t, b1, Wgt, WgtC, bsum,
                                           a1w, a1b, a2w, a2b, a1o, a2o, Z, out);

    // 3) per-level pull aggregation (phase-split for cache locality; no atomics)
    pull_agg<<<(N0 + 3) / 4, 256, 0, stream>>>(rp0, srt0, a1o, a2o, Z, out);
    pull_agg<<<(N0 + 3) / 4, 256, 0, stream>>>(rp1, srt1, a1o, a2o, Z, out);
    pull_agg<<<(N0 + 3) / 4, 256, 0, stream>>>(rp2, srt2, a1o, a2o, Z, out);
}